// Round 7
// baseline (32.790 us; speedup 1.0000x reference)
//
#include <hip/hip_runtime.h>
#include <math.h>

#define LL 500
#define BB 4
#define EE 100000
#define NBINS 24
#define TOTAL (BB * EE)
#define BLOCK 256
#define NB1 512                      // 2 blocks/CU (72KB LDS each)
#define STRIDE (NB1 * BLOCK)         // 131072
#define COORD_F (BB * LL * 3)        // 6000 floats per array

// ws layout: [0] counter (uint), partials start at float offset 32 (128B away)
#define PART_OFF 32

struct f3 { float x, y, z; };

__device__ __forceinline__ f3 sub3(f3 a, f3 b) {
    f3 r; r.x = a.x - b.x; r.y = a.y - b.y; r.z = a.z - b.z; return r;
}
__device__ __forceinline__ f3 cross3(f3 a, f3 b) {
    f3 r;
    r.x = a.y * b.z - a.z * b.y;
    r.y = a.z * b.x - a.x * b.z;
    r.z = a.x * b.y - a.y * b.x;
    return r;
}
__device__ __forceinline__ float dot3(f3 a, f3 b) {
    return fmaf(a.x, b.x, fmaf(a.y, b.y, a.z * b.z));
}

__device__ __forceinline__ float item_val(
    const float* __restrict__ lds, const float* __restrict__ coeff,
    int b, int x, int y)
{
    const float* lN  = &lds[b * (LL * 3)];
    const float* lCA = &lds[COORD_F + b * (LL * 3)];
    const float* lCB = &lds[2 * COORD_F + b * (LL * 3)];

    f3 xN, xCA, xCB, yCB;
    xN.x  = lN [3 * x]; xN.y  = lN [3 * x + 1]; xN.z  = lN [3 * x + 2];
    xCA.x = lCA[3 * x]; xCA.y = lCA[3 * x + 1]; xCA.z = lCA[3 * x + 2];
    xCB.x = lCB[3 * x]; xCB.y = lCB[3 * x + 1]; xCB.z = lCB[3 * x + 2];
    yCB.x = lCB[3 * y]; yCB.y = lCB[3 * y + 1]; yCB.z = lCB[3 * y + 2];

    const f3 b1 = sub3(xCA, xN);
    const f3 b2 = sub3(xCB, xCA);
    const f3 b3 = sub3(yCB, xCB);

    const f3 n1 = cross3(b1, b2);
    const f3 n2 = cross3(b2, b3);

    const float rn = rsqrtf(dot3(b2, b2));
    const f3 m = cross3(n1, b2);
    const float s = dot3(m, n2) * rn;
    const float c = dot3(n1, n2);

    const float theta = atan2f(s, c);

    const float step  = 0.261799387799149436f;      // 15 * pi / 180
    const float c0    = -3.14159265358979324f + 0.5f * step;
    const float twoPi = 6.28318530717958648f;

    const float tw = (theta < c0) ? theta + twoPi : theta;

    int seg = (int)floorf((tw - c0) / step);
    seg = seg < 0 ? 0 : (seg > NBINS - 1 ? NBINS - 1 : seg);

    const float t = tw - (c0 + (float)seg * step);

    const float4 cs = *reinterpret_cast<const float4*>(
        coeff + (((size_t)x * LL + (size_t)y) * NBINS + (size_t)seg) * 4);

    return fmaf(fmaf(fmaf(cs.w, t, cs.z), t, cs.y), t, cs.x);
}

__global__ void __launch_bounds__(BLOCK) theta_fused_kernel(
    const float* __restrict__ N,
    const float* __restrict__ CA,
    const float* __restrict__ CB,
    const float* __restrict__ coeff,
    const int* __restrict__ x_idx,
    const int* __restrict__ y_idx,
    unsigned int* __restrict__ counter,   // ws[0], memset to 0 each call
    float* __restrict__ partials,         // ws + PART_OFF floats
    float* __restrict__ out)
{
    const int base = blockIdx.x * BLOCK + threadIdx.x;   // [0, 131072)
    const int b    = base & 3;                           // batch (constant per thread)
    const int e0   = base >> 2;                          // edges stride by 32768

    // Hoist idx loads: latency hides under LDS staging.
    // Items 0..2 always in range (base + 262144 < 400000); item 3 masked.
    const bool has3 = (base + 3 * STRIDE) < TOTAL;
    const int x0 = x_idx[e0];
    const int y0 = y_idx[e0];
    const int x1 = x_idx[e0 + STRIDE / 4];
    const int y1 = y_idx[e0 + STRIDE / 4];
    const int x2 = x_idx[e0 + 2 * (STRIDE / 4)];
    const int y2 = y_idx[e0 + 2 * (STRIDE / 4)];
    const int x3 = has3 ? x_idx[e0 + 3 * (STRIDE / 4)] : 0;
    const int y3 = has3 ? y_idx[e0 + 3 * (STRIDE / 4)] : 0;

    // Stage all coords in LDS: [N | CA | CB], each (B,L,3) = 6000 floats.
    __shared__ float lds[3 * COORD_F];   // 72 KB
    {
        const float4* s0 = reinterpret_cast<const float4*>(N);
        const float4* s1 = reinterpret_cast<const float4*>(CA);
        const float4* s2 = reinterpret_cast<const float4*>(CB);
        float4* d0 = reinterpret_cast<float4*>(&lds[0]);
        float4* d1 = reinterpret_cast<float4*>(&lds[COORD_F]);
        float4* d2 = reinterpret_cast<float4*>(&lds[2 * COORD_F]);
        for (int j = threadIdx.x; j < COORD_F / 4; j += BLOCK) {
            d0[j] = s0[j];
            d1[j] = s1[j];
            d2[j] = s2[j];
        }
    }
    __syncthreads();

    float acc = item_val(lds, coeff, b, x0, y0)
              + item_val(lds, coeff, b, x1, y1)
              + item_val(lds, coeff, b, x2, y2);
    if (has3) acc += item_val(lds, coeff, b, x3, y3);

    // wave64 reduction
    #pragma unroll
    for (int off = 32; off > 0; off >>= 1)
        acc += __shfl_down(acc, off, 64);

    __shared__ float wsum[BLOCK / 64];
    __shared__ int is_last;
    const int lane = threadIdx.x & 63;
    const int wid  = threadIdx.x >> 6;
    if (lane == 0) wsum[wid] = acc;
    __syncthreads();

    if (threadIdx.x == 0) {
        const float p = wsum[0] + wsum[1] + wsum[2] + wsum[3];
        __hip_atomic_store(&partials[blockIdx.x], p,
                           __ATOMIC_RELEASE, __HIP_MEMORY_SCOPE_AGENT);
        const unsigned int old = __hip_atomic_fetch_add(
            counter, 1u, __ATOMIC_ACQ_REL, __HIP_MEMORY_SCOPE_AGENT);
        is_last = (old == NB1 - 1) ? 1 : 0;
    }
    __syncthreads();

    if (is_last) {
        // last-arriving block: reduce the 512 partials (L2-hot)
        float v = __hip_atomic_load(&partials[threadIdx.x],
                                    __ATOMIC_ACQUIRE, __HIP_MEMORY_SCOPE_AGENT)
                + __hip_atomic_load(&partials[threadIdx.x + BLOCK],
                                    __ATOMIC_ACQUIRE, __HIP_MEMORY_SCOPE_AGENT);
        #pragma unroll
        for (int off = 32; off > 0; off >>= 1)
            v += __shfl_down(v, off, 64);

        __shared__ float wsum2[BLOCK / 64];
        if (lane == 0) wsum2[wid] = v;
        __syncthreads();
        if (threadIdx.x == 0)
            out[0] = wsum2[0] + wsum2[1] + wsum2[2] + wsum2[3];
    }
}

extern "C" void kernel_launch(void* const* d_in, const int* in_sizes, int n_in,
                              void* d_out, int out_size, void* d_ws, size_t ws_size,
                              hipStream_t stream) {
    const float* N     = (const float*)d_in[0];
    const float* CA    = (const float*)d_in[1];
    const float* CB    = (const float*)d_in[2];
    const float* coeff = (const float*)d_in[3];
    const int* x_idx   = (const int*)d_in[4];
    const int* y_idx   = (const int*)d_in[5];
    float* out = (float*)d_out;

    unsigned int* counter = (unsigned int*)d_ws;
    float* partials = (float*)d_ws + PART_OFF;   // NB1 floats, write-before-read

    hipMemsetAsync(counter, 0, sizeof(unsigned int), stream);

    theta_fused_kernel<<<NB1, BLOCK, 0, stream>>>(N, CA, CB, coeff,
                                                  x_idx, y_idx,
                                                  counter, partials, out);
}

// Round 8
// 12.406 us; speedup vs baseline: 2.6430x; 2.6430x over previous
//
#include <hip/hip_runtime.h>
#include <math.h>

#define LL 500
#define BB 4
#define EE 100000
#define NBINS 24
#define TOTAL (BB * EE)
#define BLOCK 512
#define NB1 512                      // 2 blocks/CU (72KB LDS each), 16 waves/CU
#define STRIDE (NB1 * BLOCK)         // 262144
#define COORD_F (BB * LL * 3)        // 6000 floats per array

struct f3 { float x, y, z; };

__device__ __forceinline__ f3 sub3(f3 a, f3 b) {
    f3 r; r.x = a.x - b.x; r.y = a.y - b.y; r.z = a.z - b.z; return r;
}
__device__ __forceinline__ f3 cross3(f3 a, f3 b) {
    f3 r;
    r.x = a.y * b.z - a.z * b.y;
    r.y = a.z * b.x - a.x * b.z;
    r.z = a.x * b.y - a.y * b.x;
    return r;
}
__device__ __forceinline__ float dot3(f3 a, f3 b) {
    return fmaf(a.x, b.x, fmaf(a.y, b.y, a.z * b.z));
}

__device__ __forceinline__ float item_val(
    const float* __restrict__ lds, const float* __restrict__ coeff,
    int b, int x, int y)
{
    const float* lN  = &lds[b * (LL * 3)];
    const float* lCA = &lds[COORD_F + b * (LL * 3)];
    const float* lCB = &lds[2 * COORD_F + b * (LL * 3)];

    f3 xN, xCA, xCB, yCB;
    xN.x  = lN [3 * x]; xN.y  = lN [3 * x + 1]; xN.z  = lN [3 * x + 2];
    xCA.x = lCA[3 * x]; xCA.y = lCA[3 * x + 1]; xCA.z = lCA[3 * x + 2];
    xCB.x = lCB[3 * x]; xCB.y = lCB[3 * x + 1]; xCB.z = lCB[3 * x + 2];
    yCB.x = lCB[3 * y]; yCB.y = lCB[3 * y + 1]; yCB.z = lCB[3 * y + 2];

    const f3 b1 = sub3(xCA, xN);
    const f3 b2 = sub3(xCB, xCA);
    const f3 b3 = sub3(yCB, xCB);

    const f3 n1 = cross3(b1, b2);
    const f3 n2 = cross3(b2, b3);

    const float rn = rsqrtf(dot3(b2, b2));
    const f3 m = cross3(n1, b2);
    const float s = dot3(m, n2) * rn;
    const float c = dot3(n1, n2);

    const float theta = atan2f(s, c);

    const float step  = 0.261799387799149436f;      // 15 * pi / 180
    const float c0    = -3.14159265358979324f + 0.5f * step;
    const float twoPi = 6.28318530717958648f;

    const float tw = (theta < c0) ? theta + twoPi : theta;

    int seg = (int)floorf((tw - c0) / step);
    seg = seg < 0 ? 0 : (seg > NBINS - 1 ? NBINS - 1 : seg);

    const float t = tw - (c0 + (float)seg * step);

    const float4 cs = *reinterpret_cast<const float4*>(
        coeff + (((size_t)x * LL + (size_t)y) * NBINS + (size_t)seg) * 4);

    return fmaf(fmaf(fmaf(cs.w, t, cs.z), t, cs.y), t, cs.x);
}

__global__ void __launch_bounds__(BLOCK) theta_partial_kernel(
    const float* __restrict__ N,
    const float* __restrict__ CA,
    const float* __restrict__ CB,
    const float* __restrict__ coeff,
    const int* __restrict__ x_idx,
    const int* __restrict__ y_idx,
    float* __restrict__ partials)
{
    const int base = blockIdx.x * BLOCK + threadIdx.x;   // [0, 262144)
    const int b    = base & 3;                           // batch (4 lanes share edge)
    const int e0   = base >> 2;

    // Hoist idx loads: latency hides under LDS staging.
    const bool has1 = (base + STRIDE) < TOTAL;           // base < 137856
    const int x0 = x_idx[e0];
    const int y0 = y_idx[e0];
    const int x1 = has1 ? x_idx[e0 + STRIDE / 4] : 0;
    const int y1 = has1 ? y_idx[e0 + STRIDE / 4] : 0;

    // Stage all coords in LDS: [N | CA | CB], each (B,L,3) = 6000 floats = 72KB.
    __shared__ float lds[3 * COORD_F];
    {
        const float4* s0 = reinterpret_cast<const float4*>(N);
        const float4* s1 = reinterpret_cast<const float4*>(CA);
        const float4* s2 = reinterpret_cast<const float4*>(CB);
        float4* d0 = reinterpret_cast<float4*>(&lds[0]);
        float4* d1 = reinterpret_cast<float4*>(&lds[COORD_F]);
        float4* d2 = reinterpret_cast<float4*>(&lds[2 * COORD_F]);
        for (int j = threadIdx.x; j < COORD_F / 4; j += BLOCK) {   // 1500 float4
            d0[j] = s0[j];
            d1[j] = s1[j];
            d2[j] = s2[j];
        }
    }
    __syncthreads();

    float acc = item_val(lds, coeff, b, x0, y0);
    if (has1) acc += item_val(lds, coeff, b, x1, y1);

    // wave64 reduction
    #pragma unroll
    for (int off = 32; off > 0; off >>= 1)
        acc += __shfl_down(acc, off, 64);

    __shared__ float wsum[BLOCK / 64];
    const int lane = threadIdx.x & 63;
    const int wid  = threadIdx.x >> 6;
    if (lane == 0) wsum[wid] = acc;
    __syncthreads();
    if (threadIdx.x == 0) {
        float p = 0.0f;
        #pragma unroll
        for (int w = 0; w < BLOCK / 64; ++w) p += wsum[w];
        partials[blockIdx.x] = p;
    }
}

__global__ void __launch_bounds__(256) theta_reduce_kernel(
    const float* __restrict__ partials,
    float* __restrict__ out)
{
    // NB1 = 512 partials, 256 threads -> 2 each
    float v = partials[threadIdx.x] + partials[threadIdx.x + 256];

    #pragma unroll
    for (int off = 32; off > 0; off >>= 1)
        v += __shfl_down(v, off, 64);

    __shared__ float wsum[4];
    const int lane = threadIdx.x & 63;
    const int wid  = threadIdx.x >> 6;
    if (lane == 0) wsum[wid] = v;
    __syncthreads();
    if (threadIdx.x == 0)
        out[0] = wsum[0] + wsum[1] + wsum[2] + wsum[3];
}

extern "C" void kernel_launch(void* const* d_in, const int* in_sizes, int n_in,
                              void* d_out, int out_size, void* d_ws, size_t ws_size,
                              hipStream_t stream) {
    const float* N     = (const float*)d_in[0];
    const float* CA    = (const float*)d_in[1];
    const float* CB    = (const float*)d_in[2];
    const float* coeff = (const float*)d_in[3];
    const int* x_idx   = (const int*)d_in[4];
    const int* y_idx   = (const int*)d_in[5];
    float* out      = (float*)d_out;
    float* partials = (float*)d_ws;   // NB1 floats, write-before-read each call

    theta_partial_kernel<<<NB1, BLOCK, 0, stream>>>(N, CA, CB, coeff,
                                                    x_idx, y_idx, partials);
    theta_reduce_kernel<<<1, 256, 0, stream>>>(partials, out);
}

// Round 9
// 12.173 us; speedup vs baseline: 2.6936x; 1.0191x over previous
//
#include <hip/hip_runtime.h>
#include <math.h>

#define LL 500
#define BB 4
#define EE 100000
#define NBINS 24
#define TOTAL (BB * EE)
#define BLOCK 1024
#define NB1 512                      // 2 blocks/CU (72KB LDS), 32 waves/CU (max)
#define COORD_F (BB * LL * 3)        // 6000 floats per array

struct f3 { float x, y, z; };

__device__ __forceinline__ f3 sub3(f3 a, f3 b) {
    f3 r; r.x = a.x - b.x; r.y = a.y - b.y; r.z = a.z - b.z; return r;
}
__device__ __forceinline__ f3 cross3(f3 a, f3 b) {
    f3 r;
    r.x = a.y * b.z - a.z * b.y;
    r.y = a.z * b.x - a.x * b.z;
    r.z = a.x * b.y - a.y * b.x;
    return r;
}
__device__ __forceinline__ float dot3(f3 a, f3 b) {
    return fmaf(a.x, b.x, fmaf(a.y, b.y, a.z * b.z));
}

__device__ __forceinline__ float item_val(
    const float* __restrict__ lds, const float* __restrict__ coeff,
    int b, int x, int y)
{
    const float* lN  = &lds[b * (LL * 3)];
    const float* lCA = &lds[COORD_F + b * (LL * 3)];
    const float* lCB = &lds[2 * COORD_F + b * (LL * 3)];

    f3 xN, xCA, xCB, yCB;
    xN.x  = lN [3 * x]; xN.y  = lN [3 * x + 1]; xN.z  = lN [3 * x + 2];
    xCA.x = lCA[3 * x]; xCA.y = lCA[3 * x + 1]; xCA.z = lCA[3 * x + 2];
    xCB.x = lCB[3 * x]; xCB.y = lCB[3 * x + 1]; xCB.z = lCB[3 * x + 2];
    yCB.x = lCB[3 * y]; yCB.y = lCB[3 * y + 1]; yCB.z = lCB[3 * y + 2];

    const f3 b1 = sub3(xCA, xN);
    const f3 b2 = sub3(xCB, xCA);
    const f3 b3 = sub3(yCB, xCB);

    const f3 n1 = cross3(b1, b2);
    const f3 n2 = cross3(b2, b3);

    const float rn = rsqrtf(dot3(b2, b2));
    const f3 m = cross3(n1, b2);
    const float s = dot3(m, n2) * rn;
    const float c = dot3(n1, n2);

    const float theta = atan2f(s, c);

    const float step  = 0.261799387799149436f;      // 15 * pi / 180
    const float c0    = -3.14159265358979324f + 0.5f * step;
    const float twoPi = 6.28318530717958648f;

    const float tw = (theta < c0) ? theta + twoPi : theta;

    int seg = (int)floorf((tw - c0) / step);
    seg = seg < 0 ? 0 : (seg > NBINS - 1 ? NBINS - 1 : seg);

    const float t = tw - (c0 + (float)seg * step);

    const float4 cs = *reinterpret_cast<const float4*>(
        coeff + (((size_t)x * LL + (size_t)y) * NBINS + (size_t)seg) * 4);

    return fmaf(fmaf(fmaf(cs.w, t, cs.z), t, cs.y), t, cs.x);
}

__global__ void __launch_bounds__(BLOCK) theta_partial_kernel(
    const float* __restrict__ N,
    const float* __restrict__ CA,
    const float* __restrict__ CB,
    const float* __restrict__ coeff,
    const int* __restrict__ x_idx,
    const int* __restrict__ y_idx,
    float* __restrict__ partials)
{
    const int base = blockIdx.x * BLOCK + threadIdx.x;   // [0, 524288)
    const int b    = base & 3;                           // batch (4 lanes share edge)
    const int e0   = base >> 2;
    const bool has = base < TOTAL;

    // Hoist idx loads: latency hides under LDS staging.
    const int x0 = has ? x_idx[e0] : 0;
    const int y0 = has ? y_idx[e0] : 0;

    // Stage all coords in LDS: [N | CA | CB], each (B,L,3) = 6000 floats = 72KB.
    __shared__ float lds[3 * COORD_F];
    {
        const float4* s0 = reinterpret_cast<const float4*>(N);
        const float4* s1 = reinterpret_cast<const float4*>(CA);
        const float4* s2 = reinterpret_cast<const float4*>(CB);
        float4* d0 = reinterpret_cast<float4*>(&lds[0]);
        float4* d1 = reinterpret_cast<float4*>(&lds[COORD_F]);
        float4* d2 = reinterpret_cast<float4*>(&lds[2 * COORD_F]);
        for (int j = threadIdx.x; j < COORD_F / 4; j += BLOCK) {   // 1500 float4
            d0[j] = s0[j];
            d1[j] = s1[j];
            d2[j] = s2[j];
        }
    }
    __syncthreads();

    float acc = has ? item_val(lds, coeff, b, x0, y0) : 0.0f;

    // wave64 reduction
    #pragma unroll
    for (int off = 32; off > 0; off >>= 1)
        acc += __shfl_down(acc, off, 64);

    __shared__ float wsum[BLOCK / 64];
    const int lane = threadIdx.x & 63;
    const int wid  = threadIdx.x >> 6;
    if (lane == 0) wsum[wid] = acc;
    __syncthreads();
    if (threadIdx.x == 0) {
        float p = 0.0f;
        #pragma unroll
        for (int w = 0; w < BLOCK / 64; ++w) p += wsum[w];
        partials[blockIdx.x] = p;
    }
}

__global__ void __launch_bounds__(512) theta_reduce_kernel(
    const float* __restrict__ partials,
    float* __restrict__ out)
{
    // NB1 = 512 partials, 512 threads -> 1 each
    float v = partials[threadIdx.x];

    #pragma unroll
    for (int off = 32; off > 0; off >>= 1)
        v += __shfl_down(v, off, 64);

    __shared__ float wsum[8];
    const int lane = threadIdx.x & 63;
    const int wid  = threadIdx.x >> 6;
    if (lane == 0) wsum[wid] = v;
    __syncthreads();
    if (threadIdx.x == 0) {
        float r = 0.0f;
        #pragma unroll
        for (int w = 0; w < 8; ++w) r += wsum[w];
        out[0] = r;
    }
}

extern "C" void kernel_launch(void* const* d_in, const int* in_sizes, int n_in,
                              void* d_out, int out_size, void* d_ws, size_t ws_size,
                              hipStream_t stream) {
    const float* N     = (const float*)d_in[0];
    const float* CA    = (const float*)d_in[1];
    const float* CB    = (const float*)d_in[2];
    const float* coeff = (const float*)d_in[3];
    const int* x_idx   = (const int*)d_in[4];
    const int* y_idx   = (const int*)d_in[5];
    float* out      = (float*)d_out;
    float* partials = (float*)d_ws;   // NB1 floats, write-before-read each call

    theta_partial_kernel<<<NB1, BLOCK, 0, stream>>>(N, CA, CB, coeff,
                                                    x_idx, y_idx, partials);
    theta_reduce_kernel<<<1, 512, 0, stream>>>(partials, out);
}